// Round 8
// baseline (203.332 us; speedup 1.0000x reference)
//
#include <hip/hip_runtime.h>
#include <hip/hip_bf16.h>
#include <cmath>

typedef __hip_bfloat16 bf16;
typedef short v8s __attribute__((ext_vector_type(8)));   // 8 x bf16 bits
typedef short v4s __attribute__((ext_vector_type(4)));   // 4 x bf16 bits
typedef float v4f __attribute__((ext_vector_type(4)));
typedef float v16f __attribute__((ext_vector_type(16)));
typedef unsigned v4u __attribute__((ext_vector_type(4)));

#define AS1(p) ((__attribute__((address_space(1))) void*)(p))
#define AS3(p) ((__attribute__((address_space(3))) void*)(p))

__device__ __forceinline__ v4f mfma_bf16(v8s a, v8s b, v4f c) {
    return __builtin_amdgcn_mfma_f32_16x16x32_bf16(a, b, c, 0, 0, 0);
}
__device__ __forceinline__ v16f mfma32(v8s a, v8s b, v16f c) {
    return __builtin_amdgcn_mfma_f32_32x32x16_bf16(a, b, c, 0, 0, 0);
}

__device__ __forceinline__ short bf16_bits(float f) {
    return __builtin_bit_cast(short, __float2bfloat16(f));
}

__device__ __forceinline__ v8s pack4(unsigned a, unsigned b, unsigned c, unsigned d) {
    v4u u = {a, b, c, d};
    return __builtin_bit_cast(v8s, u);
}

// fused fp32 -> bf16 for x, w_in, w_out (float4 granularity)
__global__ __launch_bounds__(256)
void cvt_all(const float* __restrict__ x, const float* __restrict__ w_in,
             const float* __restrict__ w_out, bf16* __restrict__ xb,
             bf16* __restrict__ wib, bf16* __restrict__ wob)
{
    const int i = blockIdx.x * 256 + threadIdx.x;   // 0 .. 2097151
    const float* src; bf16* dst; int j;
    if (i < 1048576)      { src = x;     dst = xb;  j = i; }
    else if (i < 1835008) { src = w_in;  dst = wib; j = i - 1048576; }
    else                  { src = w_out; dst = wob; j = i - 1835008; }
    const float4 v = ((const float4*)src)[j];
    v4s p;
    p.x = bf16_bits(v.x); p.y = bf16_bits(v.y);
    p.z = bf16_bits(v.z); p.w = bf16_bits(v.w);
    ((v4s*)dst)[j] = p;
}

// C[m,n] = sum_k A[m,k] * Bt[n,k] + bias[n].  Tile: 128 x (NF*32), BK=32,
// double-buffered global_load_lds, XOR-4 swizzle. 8 waves (512 thr), 4x2 wave
// grid, XCD-contiguous block swizzle, V third written transposed to Vt.
// (unchanged from round 4 -- dropped out of top-5 there)
template<int NF>
__global__ __launch_bounds__(512, 4)
void gemm_bt(const bf16* __restrict__ A, const bf16* __restrict__ Bt,
             const float* __restrict__ bias, bf16* __restrict__ C,
             float* __restrict__ Cf, bf16* __restrict__ VtOut,
             int N, int K, int lda)
{
    constexpr int BN = NF * 32;
    __shared__ __align__(16) bf16 As[2][128 * 32];
    __shared__ __align__(16) bf16 Bs[2][BN * 32];

    const int t    = threadIdx.x;        // 0..511
    const int lane = t & 63;
    const int w    = t >> 6;             // 0..7
    const int l16  = lane & 15;
    const int quad = lane >> 4;

    const int nwg  = gridDim.x * gridDim.y;
    const int orig = blockIdx.y * gridDim.x + blockIdx.x;
    const int swz  = (orig & 7) * (nwg >> 3) + (orig >> 3);
    const int m0   = (swz / gridDim.x) * 128;
    const int n0   = (swz % gridDim.x) * BN;

    const int wm   = (w & 3) * 32;            // 4 m-chunks of 32 rows
    const int wn   = (w >> 2) * (NF * 16);    // 2 n-chunks of NF*16 cols

    const v4f zf = {0.f, 0.f, 0.f, 0.f};
    v4f acc[2][NF];
#pragma unroll
    for (int i = 0; i < 2; ++i)
#pragma unroll
        for (int j = 0; j < NF; ++j) acc[i][j] = zf;

    const int sr = t >> 2;
    const int g  = ((t & 3) ^ ((sr >> 1) & 3)) * 8;
    const bf16* gA = A  + (size_t)(m0 + sr) * lda + g;
    const bf16* gB = Bt + (size_t)(n0 + sr) * K + g;

    auto stage = [&](int kt, int buf) {
        const int k0 = kt * 32;
        __builtin_amdgcn_global_load_lds(AS1(gA + k0), AS3((char*)&As[buf][0] + t * 16), 16, 0, 0);
        if (NF == 4 || t < 256)   // B has BN rows; wave-uniform guard
            __builtin_amdgcn_global_load_lds(AS1(gB + k0), AS3((char*)&Bs[buf][0] + t * 16), 16, 0, 0);
    };

    stage(0, 0);
    const int KT = K >> 5;
    const int xs = ((l16 >> 1) & 3) * 8;   // read-side chunk swizzle
    for (int kt = 0; kt < KT; ++kt) {
        const int buf = kt & 1;
        __syncthreads();                    // buf staged; prev reads of buf^1 done
        if (kt + 1 < KT) stage(kt + 1, buf ^ 1);

        v8s af[2], bfr[NF];
#pragma unroll
        for (int mi = 0; mi < 2; ++mi)
            af[mi] = *(const v8s*)(&As[buf][0] + (wm + mi * 16 + l16) * 32
                                   + ((quad * 8) ^ xs));
#pragma unroll
        for (int ni = 0; ni < NF; ++ni)
            bfr[ni] = *(const v8s*)(&Bs[buf][0] + (wn + ni * 16 + l16) * 32
                                    + ((quad * 8) ^ xs));
#pragma unroll
        for (int mi = 0; mi < 2; ++mi)
#pragma unroll
            for (int ni = 0; ni < NF; ++ni)
                acc[mi][ni] = mfma_bf16(af[mi], bfr[ni], acc[mi][ni]);
    }

    // epilogue: D[row=quad*4+r][col=l16] per 16x16 tile (m91-verified layout)
    if (VtOut != nullptr && n0 >= 2048) {
        const int bb   = m0 >> 11;            // batch (m0 multiple of 128)
        const int srow = (m0 & 2047) + wm;    // s base for this wave
#pragma unroll
        for (int ni = 0; ni < NF; ++ni) {
            const int col = n0 + wn + ni * 16 + l16;
            const int hd  = col - 2048;       // h*64 + d
            const float bv = bias[col];
            bf16* vdst = VtOut + (size_t)(bb * 1024 + hd) * 2048 + srow;
#pragma unroll
            for (int mi = 0; mi < 2; ++mi) {
                v4s p;
#pragma unroll
                for (int r = 0; r < 4; ++r)
                    p[r] = bf16_bits(acc[mi][ni][r] + bv);
                *(v4s*)(vdst + mi * 16 + quad * 4) = p;
            }
        }
    } else {
#pragma unroll
        for (int ni = 0; ni < NF; ++ni) {
            const int col = n0 + wn + ni * 16 + l16;
            const float bv = bias[col];
#pragma unroll
            for (int mi = 0; mi < 2; ++mi) {
#pragma unroll
                for (int r = 0; r < 4; ++r) {
                    const int row = m0 + wm + mi * 16 + quad * 4 + r;
                    const float fv = acc[mi][ni][r] + bv;
                    if (Cf) Cf[(size_t)row * N + col] = fv;
                    else    C [(size_t)row * N + col] = __float2bfloat16(fv);
                }
            }
        }
    }
}

// Causal flash attention v8: 1024 blocks x 128 threads = 2 fat waves x 32 q-rows,
// each wave owns the FULL 64-k tile (no k-split, no combine). FRAGMENT-ORDERED
// LDS (lane-linear reads = zero bank conflicts by construction; scattered global
// staging proven benign in r5 vs r7). 32x32x16 MFMA, swapped QK^T, in-register
// softmax (T12 cvt_pk+permlane), static-max p = exp(s/8-14), exp2f, setprio,
// double-buffered global_load_lds, XCD head-locality, heavy-first qb.
//
// K LDS slot s = ks*256 + c*64 + lane  holds K[32ks + (lane&31)][16c + 8(lane>>5) + j]
// V LDS slot s = hf*256 + ks*64 + lane holds V[16ks + 8(lane>>5) + j][d=(lane&31)+32hf]
// Read at (ks,c)/(hf,ks): elem = base + lane*8  (lane-linear).
// Stage: thread t, instr i -> slot 128i + t; global source:
//   K: row (t&31) + 32*(i>>1), d = d0 + 32*(i&1),  d0 = 16*((t>>6)&1) + 8*((t>>5)&1)
//   V: Vt-row d = (t&31) + 32*(i>>1), s-col = d0 + 32*(i&1)
#define M_STATIC 14.0f
#define L2E 1.4426950408889634f

__device__ __forceinline__ void softpack(v16f s, int kg0, int qg, bool mask, int hi,
                                         float& lsum, v8s& paE, v8s& paO)
{
    float p[16];
#pragma unroll
    for (int r = 0; r < 16; ++r) {
        float pv = exp2f(fmaf(s[r], 0.125f * L2E, -M_STATIC * L2E));
        if (mask) {
            const int kg = kg0 + (r & 3) + 8 * (r >> 2) + 4 * hi;
            if (kg > qg) pv = 0.f;
        }
        lsum += pv;
        p[r] = pv;
    }
    unsigned P0[4], P1[4];
#pragma unroll
    for (int m = 0; m < 4; ++m) {
        asm("v_cvt_pk_bf16_f32 %0, %1, %2" : "=v"(P0[m]) : "v"(p[4 * m]),     "v"(p[4 * m + 1]));
        asm("v_cvt_pk_bf16_f32 %0, %1, %2" : "=v"(P1[m]) : "v"(p[4 * m + 2]), "v"(p[4 * m + 3]));
    }
    auto sA = __builtin_amdgcn_permlane32_swap(P0[0], P0[1], false, false);
    auto sB = __builtin_amdgcn_permlane32_swap(P1[0], P1[1], false, false);
    auto sC = __builtin_amdgcn_permlane32_swap(P0[2], P0[3], false, false);
    auto sD = __builtin_amdgcn_permlane32_swap(P1[2], P1[3], false, false);
    paE = pack4(sA[0], sB[0], sA[1], sB[1]);
    paO = pack4(sC[0], sD[0], sC[1], sD[1]);
}

__global__ __launch_bounds__(128, 2)
void attn(bf16* __restrict__ qkv, const bf16* __restrict__ Vt)
{
    __shared__ __align__(16) bf16 Ks[2][64 * 64];   // fragment-ordered, 8KB each
    __shared__ __align__(16) bf16 Vs[2][64 * 64];

    const int t    = threadIdx.x;        // 0..127
    const int lane = t & 63;
    const int wq   = t >> 6;             // 0,1: q-chunk of 32 rows
    const int l31  = lane & 31;
    const int hi   = lane >> 5;
    const int id   = blockIdx.x;         // 1024 blocks
    // XCD-local head mapping: xcd = id&7 owns bh in [4*xcd, 4*xcd+4); heavy-first qb
    const int j    = id >> 3;            // 0..127
    const int bh   = (id & 7) * 4 + (j & 3);
    const int qb   = 31 - (j >> 2);      // 64-row supertile 31..0 (heavy first)
    const int b = bh >> 4, h = bh & 15;
    const int T = qb + 1;                // 64-wide k-tiles to the causal frontier
    const int rowq  = qb * 64 + wq * 32; // wave's first q-row
    const int qg    = rowq + l31;        // this lane's q row
    const int ndiag = 2 * qb + wq;       // wave diagonal index (32-units)

    // Q fragments (B-operand): qf[c] = Q[qg][16c + 8hi + j]
    v8s qf[4];
    {
        const bf16* Qb = qkv + (size_t)(b * 2048 + qg) * 3072 + h * 64 + hi * 8;
#pragma unroll
        for (int c = 0; c < 4; ++c) qf[c] = *(const v8s*)(Qb + c * 16);
    }

    // fragment-order staging bases (see header comment)
    const int r31 = t & 31;
    const int d0  = 16 * ((t >> 6) & 1) + 8 * ((t >> 5) & 1);
    const bf16* kA = qkv + (size_t)(b * 2048 + r31) * 3072 + 1024 + h * 64 + d0;
    const bf16* kB = kA + (size_t)32 * 3072;
    const bf16* vA = Vt + (size_t)(bh * 64 + r31) * 2048 + d0;
    const bf16* vB = vA + (size_t)32 * 2048;

    auto stage = [&](int bufi) {
        char* kd = (char*)&Ks[bufi][0] + t * 16;
        char* vd = (char*)&Vs[bufi][0] + t * 16;
        __builtin_amdgcn_global_load_lds(AS1(kA),      AS3(kd),        16, 0, 0);
        __builtin_amdgcn_global_load_lds(AS1(kA + 32), AS3(kd + 2048), 16, 0, 0);
        __builtin_amdgcn_global_load_lds(AS1(kB),      AS3(kd + 4096), 16, 0, 0);
        __builtin_amdgcn_global_load_lds(AS1(kB + 32), AS3(kd + 6144), 16, 0, 0);
        __builtin_amdgcn_global_load_lds(AS1(vA),      AS3(vd),        16, 0, 0);
        __builtin_amdgcn_global_load_lds(AS1(vA + 32), AS3(vd + 2048), 16, 0, 0);
        __builtin_amdgcn_global_load_lds(AS1(vB),      AS3(vd + 4096), 16, 0, 0);
        __builtin_amdgcn_global_load_lds(AS1(vB + 32), AS3(vd + 6144), 16, 0, 0);
    };

    stage(0);
    kA += (size_t)64 * 3072; kB += (size_t)64 * 3072;
    vA += 64; vB += 64;

    v16f o0 = {}, o1 = {};
    float lsum = 0.f;
    const int fb = lane * 8;             // lane-linear fragment base (elems)

    for (int tile = 0; tile < T; ++tile) {
        const int buf = tile & 1;
        __syncthreads();                 // staging of `tile` complete; prior reads done
        if (tile + 1 < T) {
            stage(buf ^ 1);
            kA += (size_t)64 * 3072; kB += (size_t)64 * 3072;
            vA += 64; vB += 64;
        }

        const int m0_ = 2 * tile;        // k 32-row subtile indices
        const int m1_ = m0_ + 1;
        if (m0_ > ndiag) continue;       // wave fully past its causal frontier

        const bf16* Kb = &Ks[buf][0];
        const bf16* Vb = &Vs[buf][0];

        if (m1_ <= ndiag) {
            // hot path: both k-halves active; s0 never masked here (m0_ < ndiag)
            v16f s0 = {}, s1 = {};
            __builtin_amdgcn_s_setprio(1);
#pragma unroll
            for (int c = 0; c < 4; ++c) {
                s0 = mfma32(*(const v8s*)(Kb + c * 512 + fb),        qf[c], s0);
                s1 = mfma32(*(const v8s*)(Kb + 2048 + c * 512 + fb), qf[c], s1);
            }
            __builtin_amdgcn_s_setprio(0);
            v8s pa0, pa1, pa2, pa3;
            softpack(s0, tile * 64,      qg, false,        hi, lsum, pa0, pa1);
            softpack(s1, tile * 64 + 32, qg, m1_ == ndiag, hi, lsum, pa2, pa3);

            __builtin_amdgcn_s_setprio(1);
            o0 = mfma32(pa0, *(const v8s*)(Vb + fb),               o0);
            o1 = mfma32(pa0, *(const v8s*)(Vb + 2048 + fb),        o1);
            o0 = mfma32(pa1, *(const v8s*)(Vb + 512 + fb),         o0);
            o1 = mfma32(pa1, *(const v8s*)(Vb + 2560 + fb),        o1);
            o0 = mfma32(pa2, *(const v8s*)(Vb + 1024 + fb),        o0);
            o1 = mfma32(pa2, *(const v8s*)(Vb + 3072 + fb),        o1);
            o0 = mfma32(pa3, *(const v8s*)(Vb + 1536 + fb),        o0);
            o1 = mfma32(pa3, *(const v8s*)(Vb + 3584 + fb),        o1);
            __builtin_amdgcn_s_setprio(0);
        } else {
            // frontier: only the low k-half, masked iff on the diagonal
            v16f s0 = {};
#pragma unroll
            for (int c = 0; c < 4; ++c)
                s0 = mfma32(*(const v8s*)(Kb + c * 512 + fb), qf[c], s0);
            v8s pa0, pa1;
            softpack(s0, tile * 64, qg, m0_ == ndiag, hi, lsum, pa0, pa1);

            o0 = mfma32(pa0, *(const v8s*)(Vb + fb),        o0);
            o1 = mfma32(pa0, *(const v8s*)(Vb + 2048 + fb), o1);
            o0 = mfma32(pa1, *(const v8s*)(Vb + 512 + fb),  o0);
            o1 = mfma32(pa1, *(const v8s*)(Vb + 2560 + fb), o1);
        }
    }

    // full row sum: own-hi partial + partner half, then broadcast per output row
    const float lt = lsum + __shfl_xor(lsum, 32);

    // write attention output into the dead V-third of qkv (cols 2048+)
    bf16* dst0 = qkv + (size_t)(b * 2048 + rowq) * 3072 + 2048 + h * 64 + l31;
#pragma unroll
    for (int r = 0; r < 16; ++r) {
        const int q = (r & 3) + 8 * (r >> 2) + 4 * hi;   // O row for this reg
        const float rs  = fmaxf(__shfl(lt, q), 1e-30f);
        const float inv = 1.0f / rs;
        bf16* dst = dst0 + (size_t)q * 3072;
        dst[0]  = __float2bfloat16(o0[r] * inv);
        dst[32] = __float2bfloat16(o1[r] * inv);
    }
}

extern "C" void kernel_launch(void* const* d_in, const int* in_sizes, int n_in,
                              void* d_out, int out_size, void* d_ws, size_t ws_size,
                              hipStream_t stream)
{
    (void)in_sizes; (void)n_in; (void)out_size; (void)ws_size;
    const float* x     = (const float*)d_in[0];
    const float* w_in  = (const float*)d_in[1];
    const float* b_in  = (const float*)d_in[2];
    const float* w_out = (const float*)d_in[3];
    const float* b_out = (const float*)d_in[4];
    float* out = (float*)d_out;   // fp32 output [4096][1024]

    bf16* ws     = (bf16*)d_ws;
    bf16* xb     = ws;                           // [4096][1024]   8.4 MB
    bf16* w_inb  = xb     + (size_t)4096 * 1024; // [3072][1024]   6.3 MB
    bf16* w_outb = w_inb  + (size_t)3072 * 1024; // [1024][1024]   2.1 MB
    bf16* qkv    = w_outb + (size_t)1024 * 1024; // [4096][3072]  25.2 MB
    bf16* vt     = (bf16*)d_out;                 // [32*64][2048] scratch in d_out
                                                 // (dead before final GEMM writes out)

    cvt_all<<<8192, 256, 0, stream>>>(x, w_in, w_out, xb, w_inb, w_outb);

    // QKV projection: x[4096,1024] @ w_in^T + b_in -> qkv; V third written
    // transposed straight into vt (fused vtrans). 8-wave blocks, XCD swizzle.
    gemm_bt<4><<<dim3(24, 32), dim3(512), 0, stream>>>(xb, w_inb, b_in, qkv, nullptr,
                                                       vt, 3072, 1024, 1024);
    // causal flash attention v8: 1024 blocks, 2 fat waves, fragment-ordered LDS
    attn<<<1024, 128, 0, stream>>>(qkv, vt);
    // output projection -> fp32 d_out
    gemm_bt<2><<<dim3(16, 32), dim3(512), 0, stream>>>(qkv + 2048, w_outb, b_out, nullptr,
                                                       out, nullptr, 1024, 1024, 3072);
}

// Round 9
// 184.148 us; speedup vs baseline: 1.1042x; 1.1042x over previous
//
#include <hip/hip_runtime.h>
#include <hip/hip_bf16.h>
#include <cmath>

typedef __hip_bfloat16 bf16;
typedef short v8s __attribute__((ext_vector_type(8)));   // 8 x bf16 bits
typedef short v4s __attribute__((ext_vector_type(4)));   // 4 x bf16 bits
typedef float v4f __attribute__((ext_vector_type(4)));

#define AS1(p) ((__attribute__((address_space(1))) void*)(p))
#define AS3(p) ((__attribute__((address_space(3))) void*)(p))

__device__ __forceinline__ v4f mfma_bf16(v8s a, v8s b, v4f c) {
    return __builtin_amdgcn_mfma_f32_16x16x32_bf16(a, b, c, 0, 0, 0);
}

__device__ __forceinline__ short bf16_bits(float f) {
    return __builtin_bit_cast(short, __float2bfloat16(f));
}

// fused fp32 -> bf16 for x, w_in, w_out (float4 granularity)
__global__ __launch_bounds__(256)
void cvt_all(const float* __restrict__ x, const float* __restrict__ w_in,
             const float* __restrict__ w_out, bf16* __restrict__ xb,
             bf16* __restrict__ wib, bf16* __restrict__ wob)
{
    const int i = blockIdx.x * 256 + threadIdx.x;   // 0 .. 2097151
    const float* src; bf16* dst; int j;
    if (i < 1048576)      { src = x;     dst = xb;  j = i; }
    else if (i < 1835008) { src = w_in;  dst = wib; j = i - 1048576; }
    else                  { src = w_out; dst = wob; j = i - 1835008; }
    const float4 v = ((const float4*)src)[j];
    v4s p;
    p.x = bf16_bits(v.x); p.y = bf16_bits(v.y);
    p.z = bf16_bits(v.z); p.w = bf16_bits(v.w);
    ((v4s*)dst)[j] = p;
}

// C[m,n] = sum_k A[m,k] * Bt[n,k] + bias[n].  Tile: 128 x (NF*32), BK=32,
// double-buffered global_load_lds, XOR-4 swizzle. 8 waves (512 thr), 4x2 wave
// grid, XCD-contiguous block swizzle, V third written transposed to Vt.
// (proven in rounds 4-8)
template<int NF>
__global__ __launch_bounds__(512, 4)
void gemm_bt(const bf16* __restrict__ A, const bf16* __restrict__ Bt,
             const float* __restrict__ bias, bf16* __restrict__ C,
             float* __restrict__ Cf, bf16* __restrict__ VtOut,
             int N, int K, int lda)
{
    constexpr int BN = NF * 32;
    __shared__ __align__(16) bf16 As[2][128 * 32];
    __shared__ __align__(16) bf16 Bs[2][BN * 32];

    const int t    = threadIdx.x;        // 0..511
    const int lane = t & 63;
    const int w    = t >> 6;             // 0..7
    const int l16  = lane & 15;
    const int quad = lane >> 4;

    const int nwg  = gridDim.x * gridDim.y;
    const int orig = blockIdx.y * gridDim.x + blockIdx.x;
    const int swz  = (orig & 7) * (nwg >> 3) + (orig >> 3);
    const int m0   = (swz / gridDim.x) * 128;
    const int n0   = (swz % gridDim.x) * BN;

    const int wm   = (w & 3) * 32;            // 4 m-chunks of 32 rows
    const int wn   = (w >> 2) * (NF * 16);    // 2 n-chunks of NF*16 cols

    const v4f zf = {0.f, 0.f, 0.f, 0.f};
    v4f acc[2][NF];
#pragma unroll
    for (int i = 0; i < 2; ++i)
#pragma unroll
        for (int j = 0; j < NF; ++j) acc[i][j] = zf;

    const int sr = t >> 2;
    const int g  = ((t & 3) ^ ((sr >> 1) & 3)) * 8;
    const bf16* gA = A  + (size_t)(m0 + sr) * lda + g;
    const bf16* gB = Bt + (size_t)(n0 + sr) * K + g;

    auto stage = [&](int kt, int buf) {
        const int k0 = kt * 32;
        __builtin_amdgcn_global_load_lds(AS1(gA + k0), AS3((char*)&As[buf][0] + t * 16), 16, 0, 0);
        if (NF == 4 || t < 256)   // B has BN rows; wave-uniform guard
            __builtin_amdgcn_global_load_lds(AS1(gB + k0), AS3((char*)&Bs[buf][0] + t * 16), 16, 0, 0);
    };

    stage(0, 0);
    const int KT = K >> 5;
    const int xs = ((l16 >> 1) & 3) * 8;   // read-side chunk swizzle
    for (int kt = 0; kt < KT; ++kt) {
        const int buf = kt & 1;
        __syncthreads();                    // buf staged; prev reads of buf^1 done
        if (kt + 1 < KT) stage(kt + 1, buf ^ 1);

        v8s af[2], bfr[NF];
#pragma unroll
        for (int mi = 0; mi < 2; ++mi)
            af[mi] = *(const v8s*)(&As[buf][0] + (wm + mi * 16 + l16) * 32
                                   + ((quad * 8) ^ xs));
#pragma unroll
        for (int ni = 0; ni < NF; ++ni)
            bfr[ni] = *(const v8s*)(&Bs[buf][0] + (wn + ni * 16 + l16) * 32
                                    + ((quad * 8) ^ xs));
#pragma unroll
        for (int mi = 0; mi < 2; ++mi)
#pragma unroll
            for (int ni = 0; ni < NF; ++ni)
                acc[mi][ni] = mfma_bf16(af[mi], bfr[ni], acc[mi][ni]);
    }

    // epilogue: D[row=quad*4+r][col=l16] per 16x16 tile (m91-verified layout)
    if (VtOut != nullptr && n0 >= 2048) {
        const int bb   = m0 >> 11;            // batch (m0 multiple of 128)
        const int srow = (m0 & 2047) + wm;    // s base for this wave
#pragma unroll
        for (int ni = 0; ni < NF; ++ni) {
            const int col = n0 + wn + ni * 16 + l16;
            const int hd  = col - 2048;       // h*64 + d
            const float bv = bias[col];
            bf16* vdst = VtOut + (size_t)(bb * 1024 + hd) * 2048 + srow;
#pragma unroll
            for (int mi = 0; mi < 2; ++mi) {
                v4s p;
#pragma unroll
                for (int r = 0; r < 4; ++r)
                    p[r] = bf16_bits(acc[mi][ni][r] + bv);
                *(v4s*)(vdst + mi * 16 + quad * 4) = p;
            }
        }
    } else {
#pragma unroll
        for (int ni = 0; ni < NF; ++ni) {
            const int col = n0 + wn + ni * 16 + l16;
            const float bv = bias[col];
#pragma unroll
            for (int mi = 0; mi < 2; ++mi) {
#pragma unroll
                for (int r = 0; r < 4; ++r) {
                    const int row = m0 + wm + mi * 16 + quad * 4 + r;
                    const float fv = acc[mi][ni][r] + bv;
                    if (Cf) Cf[(size_t)row * N + col] = fv;
                    else    C [(size_t)row * N + col] = __float2bfloat16(fv);
                }
            }
        }
    }
}

// Block-cooperative causal flash attention — REVERT to the measured-fastest
// r0 structure (44.7 us): 64 q-rows/block (16/wave), 16x16x32 MFMA, P staged
// through per-wave LDS (Ps), one barrier/tile, double-buffered K/V via
// global_load_lds, XOR-8 swizzled LDS rows, static-max softmax.
// Cross-round evidence (r2-r8): every 32x32 "improvement" lost to this via
// reduced resident-wave overlap; duration tracks occupancy, not conflicts.
// Tweaks only: XCD head-locality block remap, exp2f fold, setprio (T5, m191).
#define M_STATIC 14.0f
#define L2E 1.4426950408889634f
__global__ __launch_bounds__(256)
void attn(bf16* __restrict__ qkv, const bf16* __restrict__ Vt)
{
    __shared__ __align__(16) bf16 Ks[2][64 * 64];   // [krow][d-chunk swizzled]
    __shared__ __align__(16) bf16 Vs[2][64 * 64];   // [d][s-chunk swizzled]
    __shared__ __align__(16) short Ps[4][16 * 72];  // per-wave P, stride 72 (pad)

    const int t    = threadIdx.x;
    const int lane = t & 63;
    const int w    = t >> 6;
    const int l16  = lane & 15;
    const int quad = lane >> 4;
    const int id   = blockIdx.x;          // 1024 blocks
    // XCD-local head mapping: xcd = id&7 owns bh in [4*xcd,4*xcd+4); heavy-first qb
    const int j    = id >> 3;             // 0..127
    const int bh   = (id & 7) * 4 + (j & 3);
    const int qb   = 31 - (j >> 2);       // heavy-first: qb 31..0
    const int b = bh >> 4, h = bh & 15;
    const int T = qb + 1;                 // 64-wide k-tiles to the causal frontier
    const int rowq = qb * 64 + w * 16;    // wave's first q-row

    // Q fragments (A-layout), 16 rows per wave
    v8s qf[2];
    {
        const bf16* Qb = qkv + (size_t)(b * 2048 + rowq + l16) * 3072 + h * 64 + quad * 8;
        qf[0] = *(const v8s*)(Qb);
        qf[1] = *(const v8s*)(Qb + 32);
    }

    // staging: thread t fetches 16B; LDS dst = t*16; global chunk = sc ^ (sr&7)
    const int sr  = t >> 3;          // row 0..31 within half-tile
    const int swz = ((t & 7) ^ (sr & 7)) * 8;
    const bf16* kbase = qkv + (size_t)(b * 2048 + sr) * 3072 + 1024 + h * 64 + swz;
    const bf16* vbase = Vt + (size_t)(bh * 64 + sr) * 2048 + swz;
    char* kd = (char*)&Ks[0][0] + t * 16;
    char* vd = (char*)&Vs[0][0] + t * 16;

    // stage tile 0 into buf 0
    __builtin_amdgcn_global_load_lds(AS1(kbase),                     AS3(kd),        16, 0, 0);
    __builtin_amdgcn_global_load_lds(AS1(kbase + (size_t)32 * 3072), AS3(kd + 4096), 16, 0, 0);
    __builtin_amdgcn_global_load_lds(AS1(vbase),                     AS3(vd),        16, 0, 0);
    __builtin_amdgcn_global_load_lds(AS1(vbase + (size_t)32 * 2048), AS3(vd + 4096), 16, 0, 0);

    const v4f zf = {0.f, 0.f, 0.f, 0.f};
    v4f o[4] = {zf, zf, zf, zf};
    float lsum[4] = {0.f, 0.f, 0.f, 0.f};
    short* Pw = &Ps[w][0];
    const int xsw = (l16 & 7) * 8;   // fragment-read swizzle (chunk' = c ^ (l16&7))

    for (int tile = 0; tile < T; ++tile) {
        const int buf = tile & 1;
        __syncthreads();   // staging of `tile` complete; all prior reads done
        if (tile + 1 < T) {          // prefetch next tile (drained at next barrier)
            const int nb = buf ^ 1;
            const bf16* ksrc = kbase + (size_t)((tile + 1) * 64) * 3072;
            const bf16* vsrc = vbase + (tile + 1) * 64;
            char* kdn = (char*)&Ks[nb][0] + t * 16;
            char* vdn = (char*)&Vs[nb][0] + t * 16;
            __builtin_amdgcn_global_load_lds(AS1(ksrc),                     AS3(kdn),        16, 0, 0);
            __builtin_amdgcn_global_load_lds(AS1(ksrc + (size_t)32 * 3072), AS3(kdn + 4096), 16, 0, 0);
            __builtin_amdgcn_global_load_lds(AS1(vsrc),                     AS3(vdn),        16, 0, 0);
            __builtin_amdgcn_global_load_lds(AS1(vsrc + (size_t)32 * 2048), AS3(vdn + 4096), 16, 0, 0);
        }

        // QK^T: S[16 rows][64 cols]
        v4f s[4] = {zf, zf, zf, zf};
        __builtin_amdgcn_s_setprio(1);
#pragma unroll
        for (int ks = 0; ks < 2; ++ks)
#pragma unroll
            for (int ct = 0; ct < 4; ++ct) {
                const v8s kf = *(const v8s*)(&Ks[buf][0] + (ct * 16 + l16) * 64
                                             + (((ks * 4 + quad) * 8) ^ xsw));
                s[ct] = mfma_bf16(qf[ks], kf, s[ct]);
            }
        __builtin_amdgcn_s_setprio(0);

        // exp (static max); mask only on the diagonal tile (wave-uniform branch)
        if (tile == T - 1) {
            const int colb = tile * 64;
            const int rowb = rowq + quad * 4;
#pragma unroll
            for (int ct = 0; ct < 4; ++ct) {
                const int col = colb + ct * 16 + l16;
#pragma unroll
                for (int r = 0; r < 4; ++r) {
                    const float p = (col > rowb + r)
                        ? 0.f : exp2f(fmaf(s[ct][r], 0.125f * L2E, -M_STATIC * L2E));
                    lsum[r] += p;
                    Pw[(quad * 4 + r) * 72 + ct * 16 + l16] = bf16_bits(p);
                }
            }
        } else {
#pragma unroll
            for (int ct = 0; ct < 4; ++ct)
#pragma unroll
                for (int r = 0; r < 4; ++r) {
                    const float p = exp2f(fmaf(s[ct][r], 0.125f * L2E, -M_STATIC * L2E));
                    lsum[r] += p;
                    Pw[(quad * 4 + r) * 72 + ct * 16 + l16] = bf16_bits(p);
                }
        }
        // per-wave P write->read ordering WITHOUT draining vmcnt (prefetch lives)
        asm volatile("s_waitcnt lgkmcnt(0)" ::: "memory");

        // PV: O += P[16x64] * V[64x64]
        __builtin_amdgcn_s_setprio(1);
#pragma unroll
        for (int ks = 0; ks < 2; ++ks) {
            const v8s pf = *(const v8s*)(Pw + l16 * 72 + ks * 32 + quad * 8);
#pragma unroll
            for (int nt = 0; nt < 4; ++nt) {
                const v8s vf = *(const v8s*)(&Vs[buf][0] + (nt * 16 + l16) * 64
                                             + (((ks * 4 + quad) * 8) ^ xsw));
                o[nt] = mfma_bf16(pf, vf, o[nt]);
            }
        }
        __builtin_amdgcn_s_setprio(0);
    }

    // row-sum: reduce partials across the 16 lanes holding each row (once)
#pragma unroll
    for (int r = 0; r < 4; ++r) {
        float l = lsum[r];
        l += __shfl_xor(l, 1); l += __shfl_xor(l, 2);
        l += __shfl_xor(l, 4); l += __shfl_xor(l, 8);
        lsum[r] = fmaxf(l, 1e-30f);
    }

    // write attention output into the dead V-third of qkv (cols 2048+)
#pragma unroll
    for (int nt = 0; nt < 4; ++nt)
#pragma unroll
        for (int r = 0; r < 4; ++r) {
            const int row = rowq + quad * 4 + r;
            qkv[(size_t)(b * 2048 + row) * 3072 + 2048 + h * 64 + nt * 16 + l16] =
                __float2bfloat16(o[nt][r] / lsum[r]);
        }
}

extern "C" void kernel_launch(void* const* d_in, const int* in_sizes, int n_in,
                              void* d_out, int out_size, void* d_ws, size_t ws_size,
                              hipStream_t stream)
{
    (void)in_sizes; (void)n_in; (void)out_size; (void)ws_size;
    const float* x     = (const float*)d_in[0];
    const float* w_in  = (const float*)d_in[1];
    const float* b_in  = (const float*)d_in[2];
    const float* w_out = (const float*)d_in[3];
    const float* b_out = (const float*)d_in[4];
    float* out = (float*)d_out;   // fp32 output [4096][1024]

    bf16* ws     = (bf16*)d_ws;
    bf16* xb     = ws;                           // [4096][1024]   8.4 MB
    bf16* w_inb  = xb     + (size_t)4096 * 1024; // [3072][1024]   6.3 MB
    bf16* w_outb = w_inb  + (size_t)3072 * 1024; // [1024][1024]   2.1 MB
    bf16* qkv    = w_outb + (size_t)1024 * 1024; // [4096][3072]  25.2 MB
    bf16* vt     = (bf16*)d_out;                 // [32*64][2048] scratch in d_out
                                                 // (dead before final GEMM writes out)

    cvt_all<<<8192, 256, 0, stream>>>(x, w_in, w_out, xb, w_inb, w_outb);

    // QKV projection: x[4096,1024] @ w_in^T + b_in -> qkv; V third written
    // transposed straight into vt (fused vtrans). 8-wave blocks, XCD swizzle.
    gemm_bt<4><<<dim3(24, 32), dim3(512), 0, stream>>>(xb, w_inb, b_in, qkv, nullptr,
                                                       vt, 3072, 1024, 1024);
    // causal flash attention (r0-proven 16x16 structure + XCD map/exp2f/setprio)
    attn<<<1024, 256, 0, stream>>>(qkv, vt);
    // output projection -> fp32 d_out
    gemm_bt<2><<<dim3(16, 32), dim3(512), 0, stream>>>(qkv + 2048, w_outb, b_out, nullptr,
                                                       out, nullptr, 1024, 1024, 3072);
}